// Round 1
// baseline (272.160 us; speedup 1.0000x reference)
//
#include <hip/hip_runtime.h>
#include <hip/hip_bf16.h>

#define BATCH 8192
#define NCH 8
#define CIN 512
#define COUT 512
#define NF 4096  /* in/out features */

typedef __attribute__((ext_vector_type(8))) __bf16 bf16x8;
typedef __attribute__((ext_vector_type(4))) float f32x4;

__device__ __forceinline__ bf16x8 cvt8(const float4 a, const float4 b) {
    bf16x8 p;
    p[0] = (__bf16)a.x; p[1] = (__bf16)a.y; p[2] = (__bf16)a.z; p[3] = (__bf16)a.w;
    p[4] = (__bf16)b.x; p[5] = (__bf16)b.y; p[6] = (__bf16)b.z; p[7] = (__bf16)b.w;
    return p;
}

// Per-block recompute of chunk sums + top-2 from the 2048-entry partials array.
// Deterministic (fixed reduction order) -> every block agrees.
__device__ __forceinline__ void recompute_top2(const float* __restrict__ partials,
                                               float* asums /* LDS[8] */,
                                               int& i0, int& i1) {
    const int t = threadIdx.x;
    const int c = t >> 5;        // chunk 0..7
    const int j = t & 31;
    float p = 0.f;
#pragma unroll
    for (int k = 0; k < 8; ++k) p += partials[c * 256 + j * 8 + k];
#pragma unroll
    for (int off = 16; off > 0; off >>= 1) p += __shfl_down(p, off, 32);
    if (j == 0) asums[c] = p;
    __syncthreads();
    float a[NCH];
#pragma unroll
    for (int i = 0; i < NCH; ++i) a[i] = asums[i];
    i0 = 0;
#pragma unroll
    for (int i = 1; i < NCH; ++i) if (a[i] > a[i0]) i0 = i;   // tie -> lower idx
    i1 = (i0 == 0) ? 1 : 0;
#pragma unroll
    for (int i = 0; i < NCH; ++i) if (i != i0 && a[i] > a[i1]) i1 = i;
}

// ---------------- kernel 1: |x| reduce per chunk -> partials (no atomics) ----------------
// grid (256, 8), block 256. Block (bx, c): rows bx*32..+32 of chunk c.
__global__ __launch_bounds__(256) void act_kernel(const float* __restrict__ x,
                                                  float* __restrict__ partials) {
    const int c = blockIdx.y;
    const int bx = blockIdx.x;
    const int t = threadIdx.x;
    const int wv = t >> 6;               // wave 0..3
    const int col = (t & 63) * 8;        // 0..504
    const size_t rbase = (size_t)bx * 32;
    float s = 0.f;
#pragma unroll
    for (int p = 0; p < 8; ++p) {
        const size_t r = rbase + p * 4 + wv;
        const float* src = x + r * NF + c * CIN + col;
        const float4 a0 = *(const float4*)(src);
        const float4 a1 = *(const float4*)(src + 4);
        s += fabsf(a0.x) + fabsf(a0.y) + fabsf(a0.z) + fabsf(a0.w)
           + fabsf(a1.x) + fabsf(a1.y) + fabsf(a1.z) + fabsf(a1.w);
    }
#pragma unroll
    for (int off = 32; off > 0; off >>= 1) s += __shfl_down(s, off, 64);
    __shared__ float red[4];
    const int lane = t & 63;
    if (lane == 0) red[wv] = s;
    __syncthreads();
    if (t == 0) partials[c * 256 + bx] = red[0] + red[1] + red[2] + red[3];
}

// ---------------- kernel 2: fused top2 + zero-fill + GEMM (direct fp32 reads) ----------
// grid (64, 4, 8), block 256 (4 waves). Tile 128x128, K=512 in BK=32 steps.
// Selected-chunk blocks read x/W fp32 (x is L3-resident from act pass), convert
// to bf16 in registers, ds_write_b128 into unpadded [row][32] LDS tiles
// (per-lane LDS addr = t*16 -> contiguous, conflict-free). 1-deep register
// prefetch of next K-step hides global latency across the barrier (reg loads
// don't force the vmcnt(0) barrier drain that global_load_lds does).
__global__ __launch_bounds__(256) void fused_kernel(const float* __restrict__ x,
                                                    const float* __restrict__ W,
                                                    const float* __restrict__ bias,
                                                    const float* __restrict__ partials,
                                                    float* __restrict__ out,
                                                    float* __restrict__ out_act) {
    __shared__ float asums[NCH];
    int i0, i1;
    recompute_top2(partials, asums, i0, i1);

    const int c = blockIdx.z;
    const int t = threadIdx.x;
    const size_t obase = (size_t)(blockIdx.x * 128) * NF + c * COUT + blockIdx.y * 128;

    if (blockIdx.x == 0 && blockIdx.y == 0 && c == 0 && t < NCH)
        out_act[t] = asums[t] * (1.0f / ((float)BATCH * (float)CIN));

    if (c != i0 && c != i1) {
        const float4 z = make_float4(0.f, 0.f, 0.f, 0.f);
        const int rq = t >> 5;             // 0..7
        const int cq = (t & 31) << 2;      // 0..124 step 4
#pragma unroll
        for (int p = 0; p < 16; ++p)
            *(float4*)(out + obase + (size_t)(p * 8 + rq) * NF + cq) = z;
        return;
    }

    __shared__ __bf16 Xs[128 * 32];   // [row][32], UNPADDED
    __shared__ __bf16 Wsh[128 * 32];

    const int lane = t & 63, w = t >> 6;
    const int wm = (w >> 1) * 64, wn = (w & 1) * 64;   // wave 64x64 sub-tile
    const int lr = lane & 15, lq = lane >> 4;

    // staging decomposition: thread t owns rows r0 and r0+64, k-cols k0..k0+8
    const int r0 = t >> 2;               // 0..63
    const int k0 = (t & 3) * 8;          // 0,8,16,24

    const float* xg0 = x + (size_t)(blockIdx.x * 128 + r0) * NF + c * CIN + k0;
    const float* xg1 = xg0 + (size_t)64 * NF;
    const float* wg0 = W + (size_t)c * (COUT * CIN)
                     + (size_t)(blockIdx.y * 128 + r0) * CIN + k0;
    const float* wg1 = wg0 + (size_t)64 * CIN;
    __bf16* xs0 = &Xs[r0 * 32 + k0];     // byte offset = t*16 -> conflict-free
    __bf16* xs1 = xs0 + 64 * 32;
    __bf16* ws0 = &Wsh[r0 * 32 + k0];
    __bf16* ws1 = ws0 + 64 * 32;

    f32x4 acc[4][4];
#pragma unroll
    for (int i = 0; i < 4; ++i)
#pragma unroll
        for (int j = 0; j < 4; ++j) acc[i][j] = (f32x4){0.f, 0.f, 0.f, 0.f};

    float4 a0, a1, a2, a3, b0, b1, b2, b3;

#define LOADK(off) \
    a0 = *(const float4*)(xg0 + (off));     a1 = *(const float4*)(xg0 + (off) + 4); \
    a2 = *(const float4*)(xg1 + (off));     a3 = *(const float4*)(xg1 + (off) + 4); \
    b0 = *(const float4*)(wg0 + (off));     b1 = *(const float4*)(wg0 + (off) + 4); \
    b2 = *(const float4*)(wg1 + (off));     b3 = *(const float4*)(wg1 + (off) + 4);

#define STAGE() \
    *(bf16x8*)xs0 = cvt8(a0, a1); *(bf16x8*)xs1 = cvt8(a2, a3); \
    *(bf16x8*)ws0 = cvt8(b0, b1); *(bf16x8*)ws1 = cvt8(b2, b3);

#define COMPUTE() { \
    bf16x8 av[4], bv[4]; \
    _Pragma("unroll") \
    for (int mt = 0; mt < 4; ++mt) av[mt] = *(const bf16x8*)&Xs[(wm + mt * 16 + lr) * 32 + lq * 8]; \
    _Pragma("unroll") \
    for (int nt = 0; nt < 4; ++nt) bv[nt] = *(const bf16x8*)&Wsh[(wn + nt * 16 + lr) * 32 + lq * 8]; \
    _Pragma("unroll") \
    for (int mt = 0; mt < 4; ++mt) \
    _Pragma("unroll") \
    for (int nt = 0; nt < 4; ++nt) \
        acc[mt][nt] = __builtin_amdgcn_mfma_f32_16x16x32_bf16(av[mt], bv[nt], acc[mt][nt], 0, 0, 0); }

    LOADK(0);
    for (int kk = 0; kk < CIN - 32; kk += 32) {
        STAGE();
        __syncthreads();
        LOADK(kk + 32);       // prefetch next K-step into regs, in flight across MFMA
        COMPUTE();
        __syncthreads();      // reads done before next STAGE overwrites
    }
    STAGE();
    __syncthreads();
    COMPUTE();

#undef LOADK
#undef STAGE
#undef COMPUTE

    // ---- epilogue: + bias, store fp32 ----
    float bvv[4];
#pragma unroll
    for (int nt = 0; nt < 4; ++nt)
        bvv[nt] = bias[c * COUT + blockIdx.y * 128 + wn + nt * 16 + lr];
#pragma unroll
    for (int mt = 0; mt < 4; ++mt)
#pragma unroll
        for (int nt = 0; nt < 4; ++nt)
#pragma unroll
            for (int r = 0; r < 4; ++r) {
                const int row = wm + mt * 16 + lq * 4 + r;   // C/D: row = quad*4 + reg
                const int col = wn + nt * 16 + lr;           // C/D: col = lane&15
                out[obase + (size_t)row * NF + col] = acc[mt][nt][r] + bvv[nt];
            }
}

extern "C" void kernel_launch(void* const* d_in, const int* in_sizes, int n_in,
                              void* d_out, int out_size, void* d_ws, size_t ws_size,
                              hipStream_t stream) {
    const float* x = (const float*)d_in[0];
    const float* W = (const float*)d_in[1];
    const float* b = (const float*)d_in[2];
    float* out = (float*)d_out;

    float* partials = (float*)d_ws;   // 2048 f32

    act_kernel<<<dim3(256, NCH), 256, 0, stream>>>(x, partials);
    fused_kernel<<<dim3(64, 4, NCH), 256, 0, stream>>>(x, W, b, partials, out,
                                                       out + (size_t)BATCH * NF);
}